// Round 1
// baseline (7648.969 us; speedup 1.0000x reference)
//
#include <hip/hip_runtime.h>

#define N_NODES 100000
#define N_EDGES 3200000
#define FIN 512
#define FH 16
#define FC 40

// ---------------- degree / norm ----------------

__global__ __launch_bounds__(256) void k_deg_init(float* __restrict__ deg) {
  int i = blockIdx.x * 256 + threadIdx.x;
  if (i < N_NODES) deg[i] = 1.0f;  // self-loop
}

__global__ __launch_bounds__(256) void k_deg_count(const int* __restrict__ dst,
                                                   float* __restrict__ deg) {
  int e = blockIdx.x * 256 + threadIdx.x;
  if (e < N_EDGES) atomicAdd(&deg[dst[e]], 1.0f);
}

__global__ __launch_bounds__(256) void k_rsqrt(float* __restrict__ deg) {
  int i = blockIdx.x * 256 + threadIdx.x;
  if (i < N_NODES) deg[i] = rsqrtf(deg[i]);  // deg >= 1 always
}

// ---------------- layer 1 GEMM: p1 = dinv * (x @ W1); acc1 = p1 ----------------
// 256 rows/block, K chunked by 32 through LDS (row stride 36 floats: 16B-aligned,
// spreads banks). W1 reads are wave-uniform -> scalar loads.

__global__ __launch_bounds__(256) void k_gemm1(const float* __restrict__ x,
                                               const float* __restrict__ W1,
                                               const float* __restrict__ dinv,
                                               float* __restrict__ p1,
                                               float* __restrict__ acc1) {
  __shared__ float xs[256 * 36];
  const int t = threadIdx.x;
  const int row0 = blockIdx.x * 256;
  const int row = row0 + t;
  float acc[FH];
#pragma unroll
  for (int c = 0; c < FH; c++) acc[c] = 0.0f;

  for (int kc = 0; kc < FIN; kc += 32) {
    float4 ld[8];
#pragma unroll
    for (int i = 0; i < 8; i++) {
      int idx = t + 256 * i;          // 2048 float4 tiles: 256 rows x 8 float4
      int r = idx >> 3, c4 = idx & 7;
      int gr = row0 + r;
      ld[i] = (gr < N_NODES)
                  ? *(const float4*)(x + (size_t)gr * FIN + kc + c4 * 4)
                  : make_float4(0.f, 0.f, 0.f, 0.f);
    }
    __syncthreads();  // previous chunk's LDS reads done
#pragma unroll
    for (int i = 0; i < 8; i++) {
      int idx = t + 256 * i;
      int r = idx >> 3, c4 = idx & 7;
      *(float4*)(&xs[r * 36 + c4 * 4]) = ld[i];
    }
    __syncthreads();
    float4 xr[8];
#pragma unroll
    for (int q = 0; q < 8; q++) xr[q] = *(const float4*)(&xs[t * 36 + q * 4]);
    const float4* w4 = (const float4*)(W1 + (size_t)kc * FH);  // wave-uniform
#pragma unroll
    for (int k = 0; k < 32; k++) {
      float xv = ((const float*)xr)[k];
      float4 wa = w4[k * 4 + 0], wb = w4[k * 4 + 1];
      float4 wc = w4[k * 4 + 2], wd = w4[k * 4 + 3];
      acc[0] = fmaf(xv, wa.x, acc[0]);   acc[1] = fmaf(xv, wa.y, acc[1]);
      acc[2] = fmaf(xv, wa.z, acc[2]);   acc[3] = fmaf(xv, wa.w, acc[3]);
      acc[4] = fmaf(xv, wb.x, acc[4]);   acc[5] = fmaf(xv, wb.y, acc[5]);
      acc[6] = fmaf(xv, wb.z, acc[6]);   acc[7] = fmaf(xv, wb.w, acc[7]);
      acc[8] = fmaf(xv, wc.x, acc[8]);   acc[9] = fmaf(xv, wc.y, acc[9]);
      acc[10] = fmaf(xv, wc.z, acc[10]); acc[11] = fmaf(xv, wc.w, acc[11]);
      acc[12] = fmaf(xv, wd.x, acc[12]); acc[13] = fmaf(xv, wd.y, acc[13]);
      acc[14] = fmaf(xv, wd.z, acc[14]); acc[15] = fmaf(xv, wd.w, acc[15]);
    }
  }

  if (row < N_NODES) {
    float dv = dinv[row];
#pragma unroll
    for (int c = 0; c < FH; c++) acc[c] *= dv;
#pragma unroll
    for (int q = 0; q < 4; q++) {
      float4 v = ((const float4*)acc)[q];
      *(float4*)(p1 + (size_t)row * FH + q * 4) = v;    // gather source
      *(float4*)(acc1 + (size_t)row * FH + q * 4) = v;  // self-loop init
    }
  }
}

// ---------------- layer 1 scatter: acc1[dst] += p1[src]  (4 threads/edge) -------

__global__ __launch_bounds__(256) void k_scatter1(const int* __restrict__ ei,
                                                  const float* __restrict__ p1,
                                                  float* __restrict__ acc1) {
  int tid = blockIdx.x * 256 + threadIdx.x;
  int e = tid >> 2, q = tid & 3;
  if (e >= N_EDGES) return;
  int s = ei[e];
  int d = ei[N_EDGES + e];
  float4 v = *(const float4*)(p1 + (size_t)s * FH + q * 4);
  float* a = acc1 + (size_t)d * FH + q * 4;
  atomicAdd(a + 0, v.x);
  atomicAdd(a + 1, v.y);
  atomicAdd(a + 2, v.z);
  atomicAdd(a + 3, v.w);
}

// ---- layer 2 GEMM: a1 = relu(dinv*acc1+b1); p2 = dinv*(a1@W2); acc2 = p2 ------

__global__ __launch_bounds__(256) void k_gemm2(const float* __restrict__ acc1,
                                               const float* __restrict__ dinv,
                                               const float* __restrict__ b1,
                                               const float* __restrict__ W2,
                                               float* __restrict__ p2,
                                               float* __restrict__ acc2) {
  int row = blockIdx.x * 256 + threadIdx.x;
  if (row >= N_NODES) return;
  float dv = dinv[row];
  float a1[FH];
#pragma unroll
  for (int q = 0; q < 4; q++) {
    float4 v = *(const float4*)(acc1 + (size_t)row * FH + q * 4);
    a1[q * 4 + 0] = fmaxf(fmaf(v.x, dv, b1[q * 4 + 0]), 0.f);
    a1[q * 4 + 1] = fmaxf(fmaf(v.y, dv, b1[q * 4 + 1]), 0.f);
    a1[q * 4 + 2] = fmaxf(fmaf(v.z, dv, b1[q * 4 + 2]), 0.f);
    a1[q * 4 + 3] = fmaxf(fmaf(v.w, dv, b1[q * 4 + 3]), 0.f);
  }
  float h[FC];
#pragma unroll
  for (int c = 0; c < FC; c++) h[c] = 0.f;
#pragma unroll
  for (int k = 0; k < FH; k++) {
    float av = a1[k];
    const float* wr = W2 + k * FC;  // wave-uniform -> s_load
#pragma unroll
    for (int c = 0; c < FC; c++) h[c] = fmaf(av, wr[c], h[c]);
  }
#pragma unroll
  for (int c = 0; c < FC; c++) h[c] *= dv;
#pragma unroll
  for (int q = 0; q < 10; q++) {
    float4 v = ((const float4*)h)[q];
    *(float4*)(p2 + (size_t)row * FC + q * 4) = v;
    *(float4*)(acc2 + (size_t)row * FC + q * 4) = v;  // acc2 == d_out
  }
}

// ---------------- layer 2 scatter: acc2[dst] += p2[src] (1 thread/edge) --------

__global__ __launch_bounds__(256) void k_scatter2(const int* __restrict__ ei,
                                                  const float* __restrict__ p2,
                                                  float* __restrict__ acc2) {
  int e = blockIdx.x * 256 + threadIdx.x;
  if (e >= N_EDGES) return;
  int s = ei[e];
  int d = ei[N_EDGES + e];
  const float* ps = p2 + (size_t)s * FC;
  float* a = acc2 + (size_t)d * FC;
#pragma unroll
  for (int q = 0; q < 10; q++) {
    float4 v = *(const float4*)(ps + q * 4);
    atomicAdd(a + q * 4 + 0, v.x);
    atomicAdd(a + q * 4 + 1, v.y);
    atomicAdd(a + q * 4 + 2, v.z);
    atomicAdd(a + q * 4 + 3, v.w);
  }
}

// ---------------- epilogue: out = log_softmax(dinv*acc2 + b2) ------------------

__global__ __launch_bounds__(256) void k_out(float* __restrict__ out,
                                             const float* __restrict__ dinv,
                                             const float* __restrict__ b2) {
  int row = blockIdx.x * 256 + threadIdx.x;
  if (row >= N_NODES) return;
  float dv = dinv[row];
  float v[FC];
#pragma unroll
  for (int q = 0; q < 10; q++) {
    float4 t = *(const float4*)(out + (size_t)row * FC + q * 4);
    v[q * 4 + 0] = fmaf(t.x, dv, b2[q * 4 + 0]);
    v[q * 4 + 1] = fmaf(t.y, dv, b2[q * 4 + 1]);
    v[q * 4 + 2] = fmaf(t.z, dv, b2[q * 4 + 2]);
    v[q * 4 + 3] = fmaf(t.w, dv, b2[q * 4 + 3]);
  }
  float m = -1e30f;
#pragma unroll
  for (int c = 0; c < FC; c++) m = fmaxf(m, v[c]);
  float s = 0.f;
#pragma unroll
  for (int c = 0; c < FC; c++) s += __expf(v[c] - m);
  float l = __logf(s) + m;
#pragma unroll
  for (int q = 0; q < 10; q++) {
    float4 t;
    t.x = v[q * 4 + 0] - l;
    t.y = v[q * 4 + 1] - l;
    t.z = v[q * 4 + 2] - l;
    t.w = v[q * 4 + 3] - l;
    *(float4*)(out + (size_t)row * FC + q * 4) = t;
  }
}

// ---------------- launch ----------------

extern "C" void kernel_launch(void* const* d_in, const int* in_sizes, int n_in,
                              void* d_out, int out_size, void* d_ws, size_t ws_size,
                              hipStream_t stream) {
  const float* x  = (const float*)d_in[0];
  const int*   ei = (const int*)d_in[1];  // [2, E] int32
  const float* W1 = (const float*)d_in[2];
  const float* b1 = (const float*)d_in[3];
  const float* W2 = (const float*)d_in[4];
  const float* b2 = (const float*)d_in[5];
  float* out = (float*)d_out;

  // workspace layout (floats), 16B-aligned chunks; total ~29.2 MB
  float* ws   = (float*)d_ws;
  float* deg  = ws;                 // N (becomes dinv in-place)
  float* p1   = ws + 100096;        // N*16
  float* acc1 = p1 + 1600000;       // N*16
  float* p2   = acc1 + 1600000;     // N*40

  const int nbN = (N_NODES + 255) / 256;   // 391
  const int nbE = (N_EDGES + 255) / 256;   // 12500

  k_deg_init<<<nbN, 256, 0, stream>>>(deg);
  k_deg_count<<<nbE, 256, 0, stream>>>(ei + N_EDGES, deg);
  k_rsqrt<<<nbN, 256, 0, stream>>>(deg);
  k_gemm1<<<nbN, 256, 0, stream>>>(x, W1, deg, p1, acc1);
  k_scatter1<<<(4 * N_EDGES + 255) / 256, 256, 0, stream>>>(ei, p1, acc1);
  k_gemm2<<<nbN, 256, 0, stream>>>(acc1, deg, b1, W2, p2, out);
  k_scatter2<<<nbE, 256, 0, stream>>>(ei, p2, out);
  k_out<<<nbN, 256, 0, stream>>>(out, deg, b2);
}

// Round 2
// 893.329 us; speedup vs baseline: 8.5623x; 8.5623x over previous
//
#include <hip/hip_runtime.h>

#define N_NODES 100000
#define N_EDGES 3200000
#define FIN 512
#define FH 16
#define FC 40
#define NB_N ((N_NODES + 255) / 256)   // 391
#define NB_E ((N_EDGES + 255) / 256)   // 12500

// ---------------- CSR build ----------------

__global__ __launch_bounds__(256) void k_zero(int* __restrict__ cnt) {
  int i = blockIdx.x * 256 + threadIdx.x;
  if (i < N_NODES) cnt[i] = 0;
}

__global__ __launch_bounds__(256) void k_hist(const int* __restrict__ dst,
                                              int* __restrict__ cnt) {
  int e = blockIdx.x * 256 + threadIdx.x;
  if (e < N_EDGES) atomicAdd(&cnt[dst[e]], 1);
}

__global__ __launch_bounds__(256) void k_dinv(const int* __restrict__ cnt,
                                              float* __restrict__ dinv) {
  int i = blockIdx.x * 256 + threadIdx.x;
  if (i < N_NODES) dinv[i] = rsqrtf((float)(cnt[i] + 1));  // +1 self-loop
}

__global__ __launch_bounds__(256) void k_blocksum(const int* __restrict__ cnt,
                                                  int* __restrict__ bsum) {
  __shared__ int s[256];
  int t = threadIdx.x;
  int i = blockIdx.x * 256 + t;
  s[t] = (i < N_NODES) ? cnt[i] : 0;
  __syncthreads();
#pragma unroll
  for (int d = 128; d > 0; d >>= 1) {
    if (t < d) s[t] += s[t + d];
    __syncthreads();
  }
  if (t == 0) bsum[blockIdx.x] = s[0];
}

__global__ __launch_bounds__(512) void k_scan_bsum(const int* __restrict__ bsum,
                                                   int* __restrict__ boff,
                                                   int* __restrict__ off) {
  __shared__ int s[512];
  int t = threadIdx.x;
  int v = (t < NB_N) ? bsum[t] : 0;
  s[t] = v;
  __syncthreads();
  for (int d = 1; d < 512; d <<= 1) {
    int x = (t >= d) ? s[t - d] : 0;
    __syncthreads();
    s[t] += x;
    __syncthreads();
  }
  if (t < NB_N) boff[t] = s[t] - v;  // exclusive
  if (t == 0) off[N_NODES] = N_EDGES;
}

__global__ __launch_bounds__(256) void k_scan_final(const int* __restrict__ cnt,
                                                    const int* __restrict__ boff,
                                                    int* __restrict__ off,
                                                    int* __restrict__ cur) {
  __shared__ int s[256];
  int t = threadIdx.x;
  int i = blockIdx.x * 256 + t;
  int v = (i < N_NODES) ? cnt[i] : 0;
  s[t] = v;
  __syncthreads();
  for (int d = 1; d < 256; d <<= 1) {
    int x = (t >= d) ? s[t - d] : 0;
    __syncthreads();
    s[t] += x;
    __syncthreads();
  }
  if (i < N_NODES) {
    int o = boff[blockIdx.x] + s[t] - v;
    off[i] = o;
    cur[i] = o;
  }
}

__global__ __launch_bounds__(256) void k_place(const int* __restrict__ ei,
                                               int* __restrict__ cur,
                                               int* __restrict__ csr) {
  int e = blockIdx.x * 256 + threadIdx.x;
  if (e >= N_EDGES) return;
  int s = ei[e];
  int d = ei[N_EDGES + e];
  int pos = atomicAdd(&cur[d], 1);
  csr[pos] = s;
}

// ---------------- layer 1 GEMM: p1 = dinv * (x @ W1) ----------------

__global__ __launch_bounds__(256) void k_gemm1(const float* __restrict__ x,
                                               const float* __restrict__ W1,
                                               const float* __restrict__ dinv,
                                               float* __restrict__ p1) {
  __shared__ float xs[256 * 36];
  const int t = threadIdx.x;
  const int row0 = blockIdx.x * 256;
  const int row = row0 + t;
  float acc[FH];
#pragma unroll
  for (int c = 0; c < FH; c++) acc[c] = 0.0f;

  for (int kc = 0; kc < FIN; kc += 32) {
    float4 ld[8];
#pragma unroll
    for (int i = 0; i < 8; i++) {
      int idx = t + 256 * i;
      int r = idx >> 3, c4 = idx & 7;
      int gr = row0 + r;
      ld[i] = (gr < N_NODES)
                  ? *(const float4*)(x + (size_t)gr * FIN + kc + c4 * 4)
                  : make_float4(0.f, 0.f, 0.f, 0.f);
    }
    __syncthreads();
#pragma unroll
    for (int i = 0; i < 8; i++) {
      int idx = t + 256 * i;
      int r = idx >> 3, c4 = idx & 7;
      *(float4*)(&xs[r * 36 + c4 * 4]) = ld[i];
    }
    __syncthreads();
    float4 xr[8];
#pragma unroll
    for (int q = 0; q < 8; q++) xr[q] = *(const float4*)(&xs[t * 36 + q * 4]);
    const float4* w4 = (const float4*)(W1 + (size_t)kc * FH);  // wave-uniform
#pragma unroll
    for (int k = 0; k < 32; k++) {
      float xv = ((const float*)xr)[k];
      float4 wa = w4[k * 4 + 0], wb = w4[k * 4 + 1];
      float4 wc = w4[k * 4 + 2], wd = w4[k * 4 + 3];
      acc[0] = fmaf(xv, wa.x, acc[0]);   acc[1] = fmaf(xv, wa.y, acc[1]);
      acc[2] = fmaf(xv, wa.z, acc[2]);   acc[3] = fmaf(xv, wa.w, acc[3]);
      acc[4] = fmaf(xv, wb.x, acc[4]);   acc[5] = fmaf(xv, wb.y, acc[5]);
      acc[6] = fmaf(xv, wb.z, acc[6]);   acc[7] = fmaf(xv, wb.w, acc[7]);
      acc[8] = fmaf(xv, wc.x, acc[8]);   acc[9] = fmaf(xv, wc.y, acc[9]);
      acc[10] = fmaf(xv, wc.z, acc[10]); acc[11] = fmaf(xv, wc.w, acc[11]);
      acc[12] = fmaf(xv, wd.x, acc[12]); acc[13] = fmaf(xv, wd.y, acc[13]);
      acc[14] = fmaf(xv, wd.z, acc[14]); acc[15] = fmaf(xv, wd.w, acc[15]);
    }
  }

  if (row < N_NODES) {
    float dv = dinv[row];
#pragma unroll
    for (int c = 0; c < FH; c++) acc[c] *= dv;
#pragma unroll
    for (int q = 0; q < 4; q++)
      *(float4*)(p1 + (size_t)row * FH + q * 4) = ((const float4*)acc)[q];
  }
}

// ---- gather layer 1: q = dinv * relu(dinv * (p1[self] + sum p1[src]) + b1) ----
// one wave per node; lane = 4*slot + comp; slot covers edges, comp covers float4

__global__ __launch_bounds__(256) void k_gather1(const int* __restrict__ off,
                                                 const int* __restrict__ csr,
                                                 const float* __restrict__ p1,
                                                 const float* __restrict__ dinv,
                                                 const float* __restrict__ b1,
                                                 float* __restrict__ q) {
  int lane = threadIdx.x & 63;
  int node = blockIdx.x * 4 + (threadIdx.x >> 6);
  int start = off[node];
  int end = off[node + 1];
  int slot = lane >> 2, comp = lane & 3;
  float4 acc = make_float4(0.f, 0.f, 0.f, 0.f);
  if (slot == 0)  // self-loop
    acc = *(const float4*)(p1 + (size_t)node * FH + comp * 4);
  for (int base = start; base < end; base += 16) {
    int e = base + slot;
    if (e < end) {
      int s = csr[e];
      float4 v = *(const float4*)(p1 + (size_t)s * FH + comp * 4);
      acc.x += v.x; acc.y += v.y; acc.z += v.z; acc.w += v.w;
    }
  }
#pragma unroll
  for (int m = 4; m <= 32; m <<= 1) {
    acc.x += __shfl_xor(acc.x, m);
    acc.y += __shfl_xor(acc.y, m);
    acc.z += __shfl_xor(acc.z, m);
    acc.w += __shfl_xor(acc.w, m);
  }
  float dv = dinv[node];
  if (lane < 4) {  // comp == lane
    float4 bb = *(const float4*)(b1 + lane * 4);
    float4 r;
    r.x = fmaxf(fmaf(acc.x, dv, bb.x), 0.f) * dv;
    r.y = fmaxf(fmaf(acc.y, dv, bb.y), 0.f) * dv;
    r.z = fmaxf(fmaf(acc.z, dv, bb.z), 0.f) * dv;
    r.w = fmaxf(fmaf(acc.w, dv, bb.w), 0.f) * dv;
    *(float4*)(q + (size_t)node * FH + lane * 4) = r;
  }
}

// ---- gather layer 2 + W2 matvec + log_softmax, fused ----
// t16 = dinv * (q[self] + sum q[src]);  z[c] = b2[c] + t16 . W2[:,c];
// out = z - log(sum exp(z - max))

__global__ __launch_bounds__(256) void k_gather2(const int* __restrict__ off,
                                                 const int* __restrict__ csr,
                                                 const float* __restrict__ q,
                                                 const float* __restrict__ dinv,
                                                 const float* __restrict__ W2,
                                                 const float* __restrict__ b2,
                                                 float* __restrict__ out) {
  int lane = threadIdx.x & 63;
  int node = blockIdx.x * 4 + (threadIdx.x >> 6);
  int start = off[node];
  int end = off[node + 1];
  int slot = lane >> 2, comp = lane & 3;
  float4 acc = make_float4(0.f, 0.f, 0.f, 0.f);
  if (slot == 0)  // self-loop
    acc = *(const float4*)(q + (size_t)node * FH + comp * 4);
  for (int base = start; base < end; base += 16) {
    int e = base + slot;
    if (e < end) {
      int s = csr[e];
      float4 v = *(const float4*)(q + (size_t)s * FH + comp * 4);
      acc.x += v.x; acc.y += v.y; acc.z += v.z; acc.w += v.w;
    }
  }
#pragma unroll
  for (int m = 4; m <= 32; m <<= 1) {
    acc.x += __shfl_xor(acc.x, m);
    acc.y += __shfl_xor(acc.y, m);
    acc.z += __shfl_xor(acc.z, m);
    acc.w += __shfl_xor(acc.w, m);
  }
  float dv = dinv[node];
  acc.x *= dv; acc.y *= dv; acc.z *= dv; acc.w *= dv;
  // assemble full 16-vector in every lane (comp-group xor shuffles)
  float t16[16];
  t16[comp * 4 + 0] = acc.x; t16[comp * 4 + 1] = acc.y;
  t16[comp * 4 + 2] = acc.z; t16[comp * 4 + 3] = acc.w;
#pragma unroll
  for (int m = 1; m <= 3; m++) {
    int oc = comp ^ m;
    t16[oc * 4 + 0] = __shfl_xor(acc.x, m);
    t16[oc * 4 + 1] = __shfl_xor(acc.y, m);
    t16[oc * 4 + 2] = __shfl_xor(acc.z, m);
    t16[oc * 4 + 3] = __shfl_xor(acc.w, m);
  }
  float z = -1e30f;
  if (lane < FC) {
    z = b2[lane];
#pragma unroll
    for (int k = 0; k < FH; k++) z = fmaf(t16[k], W2[k * FC + lane], z);
  }
  float mx = z;
#pragma unroll
  for (int d = 1; d < 64; d <<= 1) mx = fmaxf(mx, __shfl_xor(mx, d));
  float ex = (lane < FC) ? __expf(z - mx) : 0.f;
#pragma unroll
  for (int d = 1; d < 64; d <<= 1) ex += __shfl_xor(ex, d);
  float l = __logf(ex) + mx;
  if (lane < FC) out[(size_t)node * FC + lane] = z - l;
}

// ---------------- launch ----------------

extern "C" void kernel_launch(void* const* d_in, const int* in_sizes, int n_in,
                              void* d_out, int out_size, void* d_ws, size_t ws_size,
                              hipStream_t stream) {
  const float* x  = (const float*)d_in[0];
  const int*   ei = (const int*)d_in[1];  // [2, E] int32
  const float* W1 = (const float*)d_in[2];
  const float* b1 = (const float*)d_in[3];
  const float* W2 = (const float*)d_in[4];
  const float* b2 = (const float*)d_in[5];
  float* out = (float*)d_out;

  // workspace layout (all offsets 16B-aligned); total ~27.2 MB
  int* wsi = (int*)d_ws;
  int* cnt  = wsi;                 // 100352
  int* boff = cnt + 100352;        // 512 (NB_N=391 used)
  int* off  = boff + 512;          // 100352 (N+1 used)
  int* cur  = off + 100352;        // 100352
  int* bsum = cur + 100352;        // 512
  int* csr  = bsum + 512;          // 3200000
  float* dinv = (float*)(csr + 3200000);  // 100352
  float* p1 = dinv + 100352;       // 1600000
  float* q  = p1 + 1600000;        // 1600000

  k_zero<<<NB_N, 256, 0, stream>>>(cnt);
  k_hist<<<NB_E, 256, 0, stream>>>(ei + N_EDGES, cnt);
  k_dinv<<<NB_N, 256, 0, stream>>>(cnt, dinv);
  k_blocksum<<<NB_N, 256, 0, stream>>>(cnt, bsum);
  k_scan_bsum<<<1, 512, 0, stream>>>(bsum, boff, off);
  k_scan_final<<<NB_N, 256, 0, stream>>>(cnt, boff, off, cur);
  k_place<<<NB_E, 256, 0, stream>>>(ei, cur, csr);
  k_gemm1<<<NB_N, 256, 0, stream>>>(x, W1, dinv, p1);
  k_gather1<<<N_NODES / 4, 256, 0, stream>>>(off, csr, p1, dinv, b1, q);
  k_gather2<<<N_NODES / 4, 256, 0, stream>>>(off, csr, q, dinv, W2, b2, out);
}

// Round 3
// 578.731 us; speedup vs baseline: 13.2168x; 1.5436x over previous
//
#include <hip/hip_runtime.h>

#define N_NODES 100000
#define N_EDGES 3200000
#define FIN 512
#define FH 16
#define FC 40
#define NB_N ((N_NODES + 255) / 256)   // 391
#define NBKT 391                        // dst buckets: dst>>8, 256 nodes each
#define NBLK_P 256                      // partition blocks
#define CHUNK (N_EDGES / NBLK_P)        // 12500 exactly

// ---- kA1: per-block bucket histogram (no global atomics) ----

__global__ __launch_bounds__(256) void kA1(const int* __restrict__ dst,
                                           int* __restrict__ H) {
  __shared__ int h[NBKT];
  int t = threadIdx.x;
  for (int i = t; i < NBKT; i += 256) h[i] = 0;
  __syncthreads();
  int base = blockIdx.x * CHUNK;
  for (int i = t; i < CHUNK; i += 256) atomicAdd(&h[dst[base + i] >> 8], 1);
  __syncthreads();
  for (int i = t; i < NBKT; i += 256) H[blockIdx.x * NBKT + i] = h[i];
}

// ---- kA2: per-bucket column exclusive scan over blocks; totals T ----

__global__ __launch_bounds__(256) void kA2(const int* __restrict__ H,
                                           int* __restrict__ P,
                                           int* __restrict__ T) {
  __shared__ int s[256];
  int t = threadIdx.x, b = blockIdx.x;
  int v = H[t * NBKT + b];
  s[t] = v;
  __syncthreads();
  for (int d = 1; d < 256; d <<= 1) {
    int x = (t >= d) ? s[t - d] : 0;
    __syncthreads();
    s[t] += x;
    __syncthreads();
  }
  P[t * NBKT + b] = s[t] - v;  // exclusive sum of blocks < t for bucket b
  if (t == 255) T[b] = s[t];
}

// ---- kA3s: exclusive scan of bucket totals -> Base ----

__global__ __launch_bounds__(512) void kA3s(const int* __restrict__ T,
                                            int* __restrict__ Base,
                                            int* __restrict__ off) {
  __shared__ int s[512];
  int t = threadIdx.x;
  int v = (t < NBKT) ? T[t] : 0;
  s[t] = v;
  __syncthreads();
  for (int d = 1; d < 512; d <<= 1) {
    int x = (t >= d) ? s[t - d] : 0;
    __syncthreads();
    s[t] += x;
    __syncthreads();
  }
  if (t < NBKT) Base[t] = s[t] - v;
  if (t == 0) off[N_NODES] = N_EDGES;
}

// ---- kA3: place edges into bucket-grouped staging (LDS cursors, no global atomics)

__global__ __launch_bounds__(256) void kA3(const int* __restrict__ ei,
                                           const int* __restrict__ Base,
                                           const int* __restrict__ P,
                                           int* __restrict__ stage) {
  __shared__ int cur[NBKT];
  int t = threadIdx.x, blk = blockIdx.x;
  for (int i = t; i < NBKT; i += 256) cur[i] = Base[i] + P[blk * NBKT + i];
  __syncthreads();
  int base = blk * CHUNK;
  for (int i = t; i < CHUNK; i += 256) {
    int s = ei[base + i];
    int d = ei[N_EDGES + base + i];
    int slot = atomicAdd(&cur[d >> 8], 1);       // LDS atomic
    stage[slot] = s | ((d & 255) << 17);         // src<2^17, dlocal in 17..24
  }
}

// ---- kB: per-bucket CSR finalize: off[], dinv[], csr[] (all block-local) ----

__global__ __launch_bounds__(256) void kB(const int* __restrict__ stage,
                                          const int* __restrict__ Base,
                                          const int* __restrict__ T,
                                          int* __restrict__ off,
                                          int* __restrict__ csr,
                                          float* __restrict__ dinv) {
  __shared__ int hist[256], cursor[256], sc[256];
  int t = threadIdx.x, b = blockIdx.x;
  int base = Base[b], cnt = T[b];
  hist[t] = 0;
  __syncthreads();
  for (int i = t; i < cnt; i += 256) atomicAdd(&hist[stage[base + i] >> 17], 1);
  __syncthreads();
  int c = hist[t];
  sc[t] = c;
  __syncthreads();
  for (int d = 1; d < 256; d <<= 1) {
    int x = (t >= d) ? sc[t - d] : 0;
    __syncthreads();
    sc[t] += x;
    __syncthreads();
  }
  int excl = sc[t] - c;
  int node = b * 256 + t;
  if (node < N_NODES) {
    off[node] = base + excl;
    dinv[node] = rsqrtf((float)(c + 1));  // +1 self-loop
  }
  cursor[t] = excl;
  __syncthreads();
  for (int i = t; i < cnt; i += 256) {
    int pk = stage[base + i];
    int slot = atomicAdd(&cursor[pk >> 17], 1);  // LDS atomic
    csr[base + slot] = pk & 0x1FFFF;
  }
}

// ---------------- layer 1 GEMM: p1 = dinv * (x @ W1) ----------------

__global__ __launch_bounds__(256) void k_gemm1(const float* __restrict__ x,
                                               const float* __restrict__ W1,
                                               const float* __restrict__ dinv,
                                               float* __restrict__ p1) {
  __shared__ float xs[256 * 36];
  const int t = threadIdx.x;
  const int row0 = blockIdx.x * 256;
  const int row = row0 + t;
  float acc[FH];
#pragma unroll
  for (int c = 0; c < FH; c++) acc[c] = 0.0f;

  for (int kc = 0; kc < FIN; kc += 32) {
    float4 ld[8];
#pragma unroll
    for (int i = 0; i < 8; i++) {
      int idx = t + 256 * i;
      int r = idx >> 3, c4 = idx & 7;
      int gr = row0 + r;
      ld[i] = (gr < N_NODES)
                  ? *(const float4*)(x + (size_t)gr * FIN + kc + c4 * 4)
                  : make_float4(0.f, 0.f, 0.f, 0.f);
    }
    __syncthreads();
#pragma unroll
    for (int i = 0; i < 8; i++) {
      int idx = t + 256 * i;
      int r = idx >> 3, c4 = idx & 7;
      *(float4*)(&xs[r * 36 + c4 * 4]) = ld[i];
    }
    __syncthreads();
    float4 xr[8];
#pragma unroll
    for (int q = 0; q < 8; q++) xr[q] = *(const float4*)(&xs[t * 36 + q * 4]);
    const float4* w4 = (const float4*)(W1 + (size_t)kc * FH);  // wave-uniform
#pragma unroll
    for (int k = 0; k < 32; k++) {
      float xv = ((const float*)xr)[k];
      float4 wa = w4[k * 4 + 0], wb = w4[k * 4 + 1];
      float4 wc = w4[k * 4 + 2], wd = w4[k * 4 + 3];
      acc[0] = fmaf(xv, wa.x, acc[0]);   acc[1] = fmaf(xv, wa.y, acc[1]);
      acc[2] = fmaf(xv, wa.z, acc[2]);   acc[3] = fmaf(xv, wa.w, acc[3]);
      acc[4] = fmaf(xv, wb.x, acc[4]);   acc[5] = fmaf(xv, wb.y, acc[5]);
      acc[6] = fmaf(xv, wb.z, acc[6]);   acc[7] = fmaf(xv, wb.w, acc[7]);
      acc[8] = fmaf(xv, wc.x, acc[8]);   acc[9] = fmaf(xv, wc.y, acc[9]);
      acc[10] = fmaf(xv, wc.z, acc[10]); acc[11] = fmaf(xv, wc.w, acc[11]);
      acc[12] = fmaf(xv, wd.x, acc[12]); acc[13] = fmaf(xv, wd.y, acc[13]);
      acc[14] = fmaf(xv, wd.z, acc[14]); acc[15] = fmaf(xv, wd.w, acc[15]);
    }
  }

  if (row < N_NODES) {
    float dv = dinv[row];
#pragma unroll
    for (int c = 0; c < FH; c++) acc[c] *= dv;
#pragma unroll
    for (int q = 0; q < 4; q++)
      *(float4*)(p1 + (size_t)row * FH + q * 4) = ((const float4*)acc)[q];
  }
}

// ---- gather layer 1: q = dinv * relu(dinv * (p1[self] + sum p1[src]) + b1) ----

__global__ __launch_bounds__(256) void k_gather1(const int* __restrict__ off,
                                                 const int* __restrict__ csr,
                                                 const float* __restrict__ p1,
                                                 const float* __restrict__ dinv,
                                                 const float* __restrict__ b1,
                                                 float* __restrict__ q) {
  int lane = threadIdx.x & 63;
  int node = blockIdx.x * 4 + (threadIdx.x >> 6);
  int start = off[node];
  int end = off[node + 1];
  int slot = lane >> 2, comp = lane & 3;
  float4 acc = make_float4(0.f, 0.f, 0.f, 0.f);
  if (slot == 0)  // self-loop
    acc = *(const float4*)(p1 + (size_t)node * FH + comp * 4);
  for (int base = start; base < end; base += 16) {
    int e = base + slot;
    if (e < end) {
      int s = csr[e];
      float4 v = *(const float4*)(p1 + (size_t)s * FH + comp * 4);
      acc.x += v.x; acc.y += v.y; acc.z += v.z; acc.w += v.w;
    }
  }
#pragma unroll
  for (int m = 4; m <= 32; m <<= 1) {
    acc.x += __shfl_xor(acc.x, m);
    acc.y += __shfl_xor(acc.y, m);
    acc.z += __shfl_xor(acc.z, m);
    acc.w += __shfl_xor(acc.w, m);
  }
  float dv = dinv[node];
  if (lane < 4) {  // comp == lane
    float4 bb = *(const float4*)(b1 + lane * 4);
    float4 r;
    r.x = fmaxf(fmaf(acc.x, dv, bb.x), 0.f) * dv;
    r.y = fmaxf(fmaf(acc.y, dv, bb.y), 0.f) * dv;
    r.z = fmaxf(fmaf(acc.z, dv, bb.z), 0.f) * dv;
    r.w = fmaxf(fmaf(acc.w, dv, bb.w), 0.f) * dv;
    *(float4*)(q + (size_t)node * FH + lane * 4) = r;
  }
}

// ---- gather layer 2 + W2 matvec + log_softmax, fused ----

__global__ __launch_bounds__(256) void k_gather2(const int* __restrict__ off,
                                                 const int* __restrict__ csr,
                                                 const float* __restrict__ q,
                                                 const float* __restrict__ dinv,
                                                 const float* __restrict__ W2,
                                                 const float* __restrict__ b2,
                                                 float* __restrict__ out) {
  int lane = threadIdx.x & 63;
  int node = blockIdx.x * 4 + (threadIdx.x >> 6);
  int start = off[node];
  int end = off[node + 1];
  int slot = lane >> 2, comp = lane & 3;
  float4 acc = make_float4(0.f, 0.f, 0.f, 0.f);
  if (slot == 0)  // self-loop
    acc = *(const float4*)(q + (size_t)node * FH + comp * 4);
  for (int base = start; base < end; base += 16) {
    int e = base + slot;
    if (e < end) {
      int s = csr[e];
      float4 v = *(const float4*)(q + (size_t)s * FH + comp * 4);
      acc.x += v.x; acc.y += v.y; acc.z += v.z; acc.w += v.w;
    }
  }
#pragma unroll
  for (int m = 4; m <= 32; m <<= 1) {
    acc.x += __shfl_xor(acc.x, m);
    acc.y += __shfl_xor(acc.y, m);
    acc.z += __shfl_xor(acc.z, m);
    acc.w += __shfl_xor(acc.w, m);
  }
  float dv = dinv[node];
  acc.x *= dv; acc.y *= dv; acc.z *= dv; acc.w *= dv;
  float t16[16];
  t16[comp * 4 + 0] = acc.x; t16[comp * 4 + 1] = acc.y;
  t16[comp * 4 + 2] = acc.z; t16[comp * 4 + 3] = acc.w;
#pragma unroll
  for (int m = 1; m <= 3; m++) {
    int oc = comp ^ m;
    t16[oc * 4 + 0] = __shfl_xor(acc.x, m);
    t16[oc * 4 + 1] = __shfl_xor(acc.y, m);
    t16[oc * 4 + 2] = __shfl_xor(acc.z, m);
    t16[oc * 4 + 3] = __shfl_xor(acc.w, m);
  }
  float z = -1e30f;
  if (lane < FC) {
    z = b2[lane];
#pragma unroll
    for (int k = 0; k < FH; k++) z = fmaf(t16[k], W2[k * FC + lane], z);
  }
  float mx = z;
#pragma unroll
  for (int d = 1; d < 64; d <<= 1) mx = fmaxf(mx, __shfl_xor(mx, d));
  float ex = (lane < FC) ? __expf(z - mx) : 0.f;
#pragma unroll
  for (int d = 1; d < 64; d <<= 1) ex += __shfl_xor(ex, d);
  float l = __logf(ex) + mx;
  if (lane < FC) out[(size_t)node * FC + lane] = z - l;
}

// ---------------- launch ----------------

extern "C" void kernel_launch(void* const* d_in, const int* in_sizes, int n_in,
                              void* d_out, int out_size, void* d_ws, size_t ws_size,
                              hipStream_t stream) {
  const float* x  = (const float*)d_in[0];
  const int*   ei = (const int*)d_in[1];  // [2, E] int32
  const float* W1 = (const float*)d_in[2];
  const float* b1 = (const float*)d_in[3];
  const float* W2 = (const float*)d_in[4];
  const float* b2 = (const float*)d_in[5];
  float* out = (float*)d_out;

  // workspace (ints): H 100096 | P 100096 | T 512 | Base 512 | off 100352 |
  //                   csr 3200000 | stage 3200000 (reused: p1|q) | dinv 100352
  // total ~27.2 MB
  int* wsi  = (int*)d_ws;
  int* H    = wsi;
  int* P    = H + 100096;
  int* T    = P + 100096;
  int* Base = T + 512;
  int* off  = Base + 512;
  int* csr  = off + 100352;
  int* stage = csr + 3200000;
  float* dinv = (float*)(stage + 3200000);
  float* p1 = (float*)stage;        // stage dead after kB
  float* q  = p1 + 1600000;

  kA1 <<<NBLK_P, 256, 0, stream>>>(ei + N_EDGES, H);
  kA2 <<<NBKT,   256, 0, stream>>>(H, P, T);
  kA3s<<<1,      512, 0, stream>>>(T, Base, off);
  kA3 <<<NBLK_P, 256, 0, stream>>>(ei, Base, P, stage);
  kB  <<<NBKT,   256, 0, stream>>>(stage, Base, T, off, csr, dinv);
  k_gemm1  <<<NB_N, 256, 0, stream>>>(x, W1, dinv, p1);
  k_gather1<<<N_NODES / 4, 256, 0, stream>>>(off, csr, p1, dinv, b1, q);
  k_gather2<<<N_NODES / 4, 256, 0, stream>>>(off, csr, q, dinv, W2, b2, out);
}